// Round 1
// baseline (10950.410 us; speedup 1.0000x reference)
//
#include <hip/hip_runtime.h>
#include <hip/hip_bf16.h>

// ---------------------------------------------------------------------------
// Persistent fused 2-layer GRU + head for MI355X (gfx950).
//
// Strategy: the recurrence is latency-bound (1024 tiny sequential GEMMs).
// One persistent kernel, 128 blocks (1 per CU guaranteed by 148.5KB LDS),
// weights resident in LDS (bf16), custom device-scope barrier per time step.
// Layer 1 is pipelined one step behind layer 0 -> 513 barriers total.
// ---------------------------------------------------------------------------

namespace {
constexpr int kB  = 256;   // batch
constexpr int kT  = 512;   // time steps
constexpr int kF  = 32;    // input features
constexpr int kH  = 512;   // hidden
constexpr int kE  = 32;    // embed dim
constexpr int kPD = 30;    // predict days

constexpr int GBLK = 128;  // grid blocks (4 batch groups x 32 hidden groups)
constexpr int NTHR = 256;  // threads per block (4 waves)
constexpr int HB   = 16;   // hidden slice per block
constexpr int BB   = 64;   // batch slice per block (16 per wave)

constexpr int W0K = kH + kF;   // 544  (Whh0 | Wih0)
constexpr int W0S = W0K + 8;   // 552  padded LDS stride (bank-conflict-free)
constexpr int W1K = 2 * kH;    // 1024 (Whh1 | Wih1)
constexpr int W1S = W1K + 8;   // 1032
constexpr int LDSB = (48 * W0S + 48 * W1S) * 2;  // 152064 bytes <= 160KiB
static_assert(LDSB <= 160 * 1024, "LDS overflow");

typedef __bf16 bf16_t;
typedef __bf16 bf16x8 __attribute__((ext_vector_type(8)));
typedef float  f32x4  __attribute__((ext_vector_type(4)));

__device__ __forceinline__ float sigmoid_f(float x) {
  return 1.f / (1.f + __expf(-x));
}
__device__ __forceinline__ float tanh_f(float x) {
  float a = fabsf(x);
  float e = __expf(-2.f * a);          // e in (0,1], never overflows
  float t = (1.f - e) / (1.f + e);
  return copysignf(t, x);
}
}  // namespace

// ws layout (bytes):
//   [0,256)                     : barrier counter (uint32 at 0)
//   h0f: 2 * B*H fp32  (1MB)    : layer0 hidden master, double buffered
//   h1f: 2 * B*H fp32  (1MB)
//   h0b: 2 * B*H bf16  (512KB)  : bf16 copies for MFMA operands
//   h1b: 2 * B*H bf16  (512KB)

__launch_bounds__(NTHR, 1)
__global__ void gru_persistent(
    const float* __restrict__ seq,                                  // (B,T,F)
    const float* __restrict__ Wih0, const float* __restrict__ Whh0, // (3H,F),(3H,H)
    const float* __restrict__ bih0, const float* __restrict__ bhh0,
    const float* __restrict__ Wih1, const float* __restrict__ Whh1, // (3H,H),(3H,H)
    const float* __restrict__ bih1, const float* __restrict__ bhh1,
    float* __restrict__ h0f, float* __restrict__ h1f,
    bf16_t* __restrict__ h0b, bf16_t* __restrict__ h1b,
    unsigned* __restrict__ bar) {
  extern __shared__ char smem[];
  bf16_t* w0 = (bf16_t*)smem;                       // [48][W0S]
  bf16_t* w1 = (bf16_t*)(smem + 48 * W0S * 2);      // [48][W1S]

  const int tid  = threadIdx.x;
  const int gb   = blockIdx.x & 3;    // batch group (0..3)  -> XCD-friendly
  const int gh   = blockIdx.x >> 2;   // hidden group (0..31)
  const int hs   = gh * HB;
  const int wv   = tid >> 6;
  const int lane = tid & 63;
  const int bm   = gb * BB + wv * 16; // this wave's batch-row base (M tile)
  const int lm   = lane & 15;         // A row / B col / D col within tile
  const int lq   = lane >> 4;         // quad
  const int koff = lq * 8;            // k offset within 32-chunk

  // ---- one-time: stage weight slices into LDS as bf16 ----
  for (int r = 0; r < 48; ++r) {
    const int g = r >> 4, j = r & 15;
    const int gr = g * kH + hs + j;   // row in the 3H packing [r,z,n]
    for (int k = tid; k < W0K; k += NTHR) {
      float v = (k < kH) ? Whh0[gr * kH + k] : Wih0[gr * kF + (k - kH)];
      w0[r * W0S + k] = (bf16_t)v;
    }
    for (int k = tid; k < W1K; k += NTHR) {
      float v = (k < kH) ? Whh1[gr * kH + k] : Wih1[gr * kH + (k - kH)];
      w1[r * W1S + k] = (bf16_t)v;
    }
  }

  // per-lane biases (this lane's hidden column = hs + lm, fixed for all steps)
  const int c = hs + lm;
  const float b0r  = bih0[c] + bhh0[c];
  const float b0z  = bih0[kH + c] + bhh0[kH + c];
  const float b0nx = bih0[2 * kH + c];
  const float b0nh = bhh0[2 * kH + c];
  const float b1r  = bih1[c] + bhh1[c];
  const float b1z  = bih1[kH + c] + bhh1[kH + c];
  const float b1nx = bih1[2 * kH + c];
  const float b1nh = bhh1[2 * kH + c];

  __syncthreads();

  const int arow  = bm + lm;          // this lane's A (batch) row
  const int arowH = arow * kH;

  for (int s = 0; s < kT + 1; ++s) {
    const int pr = (s + 1) & 1;       // read parity (prev step's state)
    const int pw = s & 1;             // write parity

    // ================= layer 0 : t = s =================
    if (s < kT) {
      const int t = s;
      const bf16_t* hsrc = h0b + pr * (kB * kH);
      f32x4 aR{0.f, 0.f, 0.f, 0.f}, aZ{0.f, 0.f, 0.f, 0.f};
      f32x4 aNH{0.f, 0.f, 0.f, 0.f}, aNX{0.f, 0.f, 0.f, 0.f};

#pragma unroll 4
      for (int kc = 0; kc < 16; ++kc) {   // K = h0 (512)
        bf16x8 a = *(const bf16x8*)(hsrc + arowH + kc * 32 + koff);
        bf16x8 br = *(const bf16x8*)(w0 + (0 * 16 + lm) * W0S + kc * 32 + koff);
        bf16x8 bz = *(const bf16x8*)(w0 + (1 * 16 + lm) * W0S + kc * 32 + koff);
        bf16x8 bn = *(const bf16x8*)(w0 + (2 * 16 + lm) * W0S + kc * 32 + koff);
        aR  = __builtin_amdgcn_mfma_f32_16x16x32_bf16(a, br, aR, 0, 0, 0);
        aZ  = __builtin_amdgcn_mfma_f32_16x16x32_bf16(a, bz, aZ, 0, 0, 0);
        aNH = __builtin_amdgcn_mfma_f32_16x16x32_bf16(a, bn, aNH, 0, 0, 0);
      }
      {  // K = x_t (32), fp32 source -> bf16
        const float* xp = seq + ((size_t)arow * kT + t) * kF + koff;
        bf16x8 a;
#pragma unroll
        for (int j = 0; j < 8; ++j) a[j] = (bf16_t)xp[j];
        bf16x8 br = *(const bf16x8*)(w0 + (0 * 16 + lm) * W0S + kH + koff);
        bf16x8 bz = *(const bf16x8*)(w0 + (1 * 16 + lm) * W0S + kH + koff);
        bf16x8 bn = *(const bf16x8*)(w0 + (2 * 16 + lm) * W0S + kH + koff);
        aR  = __builtin_amdgcn_mfma_f32_16x16x32_bf16(a, br, aR, 0, 0, 0);
        aZ  = __builtin_amdgcn_mfma_f32_16x16x32_bf16(a, bz, aZ, 0, 0, 0);
        aNX = __builtin_amdgcn_mfma_f32_16x16x32_bf16(a, bn, aNX, 0, 0, 0);
      }
      // gate epilogue: lane holds col c, rows bm + lq*4 + i
      const float* hof = h0f + pr * (kB * kH);
      float* hnf = h0f + pw * (kB * kH);
      bf16_t* hnb = h0b + pw * (kB * kH);
#pragma unroll
      for (int i = 0; i < 4; ++i) {
        const int b = bm + lq * 4 + i;
        float r = sigmoid_f(aR[i] + b0r);
        float z = sigmoid_f(aZ[i] + b0z);
        float n = tanh_f((aNX[i] + b0nx) + r * (aNH[i] + b0nh));
        float ho = hof[b * kH + c];
        float hn = (1.f - z) * n + z * ho;
        hnf[b * kH + c] = hn;
        hnb[b * kH + c] = (bf16_t)hn;
      }
    }

    // ================= layer 1 : t = s-1 =================
    if (s >= 1) {
      const bf16_t* h1src = h1b + pr * (kB * kH);   // h1_{s-2}
      const bf16_t* xsrc  = h0b + pr * (kB * kH);   // out0_{s-1}
      f32x4 cR{0.f, 0.f, 0.f, 0.f}, cZ{0.f, 0.f, 0.f, 0.f};
      f32x4 cNH{0.f, 0.f, 0.f, 0.f}, cNX{0.f, 0.f, 0.f, 0.f};

#pragma unroll 4
      for (int kc = 0; kc < 16; ++kc) {   // K = h1 (512)
        bf16x8 a = *(const bf16x8*)(h1src + arowH + kc * 32 + koff);
        bf16x8 br = *(const bf16x8*)(w1 + (0 * 16 + lm) * W1S + kc * 32 + koff);
        bf16x8 bz = *(const bf16x8*)(w1 + (1 * 16 + lm) * W1S + kc * 32 + koff);
        bf16x8 bn = *(const bf16x8*)(w1 + (2 * 16 + lm) * W1S + kc * 32 + koff);
        cR  = __builtin_amdgcn_mfma_f32_16x16x32_bf16(a, br, cR, 0, 0, 0);
        cZ  = __builtin_amdgcn_mfma_f32_16x16x32_bf16(a, bz, cZ, 0, 0, 0);
        cNH = __builtin_amdgcn_mfma_f32_16x16x32_bf16(a, bn, cNH, 0, 0, 0);
      }
#pragma unroll 4
      for (int kc = 0; kc < 16; ++kc) {   // K = out0_t (512)
        bf16x8 a = *(const bf16x8*)(xsrc + arowH + kc * 32 + koff);
        bf16x8 br = *(const bf16x8*)(w1 + (0 * 16 + lm) * W1S + kH + kc * 32 + koff);
        bf16x8 bz = *(const bf16x8*)(w1 + (1 * 16 + lm) * W1S + kH + kc * 32 + koff);
        bf16x8 bn = *(const bf16x8*)(w1 + (2 * 16 + lm) * W1S + kH + kc * 32 + koff);
        cR  = __builtin_amdgcn_mfma_f32_16x16x32_bf16(a, br, cR, 0, 0, 0);
        cZ  = __builtin_amdgcn_mfma_f32_16x16x32_bf16(a, bz, cZ, 0, 0, 0);
        cNX = __builtin_amdgcn_mfma_f32_16x16x32_bf16(a, bn, cNX, 0, 0, 0);
      }
      const float* hof = h1f + pr * (kB * kH);
      float* hnf = h1f + pw * (kB * kH);
      bf16_t* hnb = h1b + pw * (kB * kH);
#pragma unroll
      for (int i = 0; i < 4; ++i) {
        const int b = bm + lq * 4 + i;
        float r = sigmoid_f(cR[i] + b1r);
        float z = sigmoid_f(cZ[i] + b1z);
        float n = tanh_f((cNX[i] + b1nx) + r * (cNH[i] + b1nh));
        float ho = hof[b * kH + c];
        float hn = (1.f - z) * n + z * ho;
        hnf[b * kH + c] = hn;
        hnb[b * kH + c] = (bf16_t)hn;
      }
    }

    // ================= device-scope barrier =================
    __syncthreads();  // all block stores issued (compiler drains vmcnt here)
    if (tid == 0) {
      __threadfence();  // release: flush to device scope (LLC)
      __hip_atomic_fetch_add(bar, 1u, __ATOMIC_ACQ_REL, __HIP_MEMORY_SCOPE_AGENT);
      const unsigned target = (unsigned)GBLK * (unsigned)(s + 1);
      int guard = 0;
      while (__hip_atomic_load(bar, __ATOMIC_ACQUIRE, __HIP_MEMORY_SCOPE_AGENT) <
             target) {
        __builtin_amdgcn_s_sleep(1);
        if (++guard > 8192) break;  // safety valve: never hang the queue
      }
      __threadfence();  // acquire: invalidate L1/L2 before next step's reads
    }
    __syncthreads();
  }
}

// ---- head: concat(h1_last, embed) -> fc1+relu -> fc2 ----
__global__ void head_kernel(const float* __restrict__ h1,     // (B,H) parity 0
                            const int* __restrict__ ticker,   // (B,)
                            const float* __restrict__ etab,   // (5000,E)
                            const float* __restrict__ fc1w,   // (H, H+E)
                            const float* __restrict__ fc1b,   // (H,)
                            const float* __restrict__ fc2w,   // (PD, H)
                            const float* __restrict__ fc2b,   // (PD,)
                            float* __restrict__ out) {        // (B, PD)
  __shared__ float xin[4][kH + kE];
  __shared__ float y1[4][kH];
  const int tid = threadIdx.x;
  const int b0 = blockIdx.x * 4;

  for (int idx = tid; idx < 4 * (kH + kE); idx += 256) {
    const int r = idx / (kH + kE), k = idx % (kH + kE);
    const int b = b0 + r;
    xin[r][k] = (k < kH) ? h1[b * kH + k] : etab[ticker[b] * kE + (k - kH)];
  }
  __syncthreads();

#pragma unroll
  for (int jj = 0; jj < 2; ++jj) {
    const int j = tid + jj * 256;
    const float* wr = fc1w + j * (kH + kE);
    float a0 = 0.f, a1 = 0.f, a2 = 0.f, a3 = 0.f;
    for (int k = 0; k < kH + kE; ++k) {
      const float w = wr[k];
      a0 += w * xin[0][k];
      a1 += w * xin[1][k];
      a2 += w * xin[2][k];
      a3 += w * xin[3][k];
    }
    const float bb = fc1b[j];
    y1[0][j] = fmaxf(a0 + bb, 0.f);
    y1[1][j] = fmaxf(a1 + bb, 0.f);
    y1[2][j] = fmaxf(a2 + bb, 0.f);
    y1[3][j] = fmaxf(a3 + bb, 0.f);
  }
  __syncthreads();

  if (tid < 4 * kPD) {
    const int r = tid / kPD, j = tid % kPD;
    const float* wr = fc2w + j * kH;
    float acc = fc2b[j];
    for (int k = 0; k < kH; ++k) acc += wr[k] * y1[r][k];
    out[(b0 + r) * kPD + j] = acc;
  }
}

extern "C" void kernel_launch(void* const* d_in, const int* in_sizes, int n_in,
                              void* d_out, int out_size, void* d_ws,
                              size_t ws_size, hipStream_t stream) {
  (void)in_sizes; (void)n_in; (void)out_size; (void)ws_size;

  const int*   ticker = (const int*)d_in[0];
  const float* seq    = (const float*)d_in[1];
  const float* etab   = (const float*)d_in[2];
  const float* Wih0   = (const float*)d_in[3];
  const float* Whh0   = (const float*)d_in[4];
  const float* bih0   = (const float*)d_in[5];
  const float* bhh0   = (const float*)d_in[6];
  const float* Wih1   = (const float*)d_in[7];
  const float* Whh1   = (const float*)d_in[8];
  const float* bih1   = (const float*)d_in[9];
  const float* bhh1   = (const float*)d_in[10];
  const float* fc1w   = (const float*)d_in[11];
  const float* fc1b   = (const float*)d_in[12];
  const float* fc2w   = (const float*)d_in[13];
  const float* fc2b   = (const float*)d_in[14];

  char* ws = (char*)d_ws;
  unsigned* bar = (unsigned*)ws;
  float*  h0f = (float*)(ws + 256);
  float*  h1f = (float*)(ws + 256 + 2 * kB * kH * 4);
  bf16_t* h0b = (bf16_t*)(ws + 256 + 4 * kB * kH * 4);
  bf16_t* h1b = (bf16_t*)(ws + 256 + 4 * kB * kH * 4 + 2 * kB * kH * 2);
  const size_t init_bytes = 256 + 4 * kB * kH * 4 + 4 * kB * kH * 2;  // ~3.0MB

  // zero: barrier counter + initial hidden states (parities read at s=0/1)
  hipMemsetAsync(d_ws, 0, init_bytes, stream);

  gru_persistent<<<GBLK, NTHR, LDSB, stream>>>(
      seq, Wih0, Whh0, bih0, bhh0, Wih1, Whh1, bih1, bhh1,
      h0f, h1f, h0b, h1b, bar);

  // final h1 lives at parity 0 (written at s=512)
  head_kernel<<<kB / 4, 256, 0, stream>>>(h1f, ticker, etab, fc1w, fc1b, fc2w,
                                          fc2b, (float*)d_out);
}

// Round 2
// 6852.877 us; speedup vs baseline: 1.5979x; 1.5979x over previous
//
#include <hip/hip_runtime.h>
#include <hip/hip_bf16.h>

// ---------------------------------------------------------------------------
// Persistent fused 2-layer GRU + head for MI355X (gfx950).
//
// R1 -> R2 changes:
//  * Barrier rebuilt: one RELEASE fence + relaxed fetch_add + RELAXED spin
//    (s_sleep) + one ACQUIRE fence. The R1 version acquired (buffer_inv =
//    full L2 invalidate) on EVERY poll iteration -> L2 invalidation storm,
//    21us/step of idle. 4 independent per-batch-group barriers (32 arrivals).
//  * Hidden-state f32 master moved into registers (owner lane of h[b,c] is
//    the same lane every step). Only bf16 exchange buffers remain in global.
//  * Layer-1's two K loops fused (h1 and out0 A-loads interleaved -> 2x
//    outstanding loads).
// ---------------------------------------------------------------------------

namespace {
constexpr int kB  = 256;   // batch
constexpr int kT  = 512;   // time steps
constexpr int kF  = 32;    // input features
constexpr int kH  = 512;   // hidden
constexpr int kE  = 32;    // embed dim
constexpr int kPD = 30;    // predict days

constexpr int GBLK = 128;  // 4 batch groups x 32 hidden groups
constexpr int NTHR = 256;  // 4 waves
constexpr int HB   = 16;   // hidden slice per block
constexpr int BB   = 64;   // batch slice per block (16 per wave)
constexpr int GRP  = 32;   // blocks per barrier group

constexpr int W0K = kH + kF;   // 544  (Whh0 | Wih0)
constexpr int W0S = W0K + 8;   // 552  (stride/2 = 276 ≡ 4 mod 8 -> good spread)
constexpr int W1K = 2 * kH;    // 1024 (Whh1 | Wih1)
constexpr int W1S = W1K + 8;   // 1032 (stride/2 = 516 ≡ 4 mod 8)
constexpr int LDSB = (48 * W0S + 48 * W1S) * 2;  // 152064 bytes
static_assert(LDSB <= 160 * 1024, "LDS overflow");

typedef __bf16 bf16_t;
typedef __bf16 bf16x8 __attribute__((ext_vector_type(8)));
typedef float  f32x4  __attribute__((ext_vector_type(4)));

__device__ __forceinline__ float sigmoid_f(float x) {
  return 1.f / (1.f + __expf(-x));
}
__device__ __forceinline__ float tanh_f(float x) {
  float a = fabsf(x);
  float e = __expf(-2.f * a);          // e in (0,1], never overflows
  float t = (1.f - e) / (1.f + e);
  return copysignf(t, x);
}
}  // namespace

// ws layout (bytes):
//   [0,1024)                 : 4 barrier counters, 256B apart
//   h0b: 2 * B*H bf16 (512KB): layer0 output exchange, double buffered
//   h1b: 2 * B*H bf16 (512KB): layer1 hidden exchange, double buffered
//   h1f: B*H fp32     (512KB): final h1 (written once at s=kT)

__launch_bounds__(NTHR, 1)
__global__ void gru_persistent(
    const float* __restrict__ seq,                                  // (B,T,F)
    const float* __restrict__ Wih0, const float* __restrict__ Whh0,
    const float* __restrict__ bih0, const float* __restrict__ bhh0,
    const float* __restrict__ Wih1, const float* __restrict__ Whh1,
    const float* __restrict__ bih1, const float* __restrict__ bhh1,
    bf16_t* __restrict__ h0b, bf16_t* __restrict__ h1b,
    float* __restrict__ h1f, unsigned* __restrict__ barbase) {
  extern __shared__ char smem[];
  bf16_t* w0 = (bf16_t*)smem;                       // [48][W0S]
  bf16_t* w1 = (bf16_t*)(smem + 48 * W0S * 2);      // [48][W1S]

  const int tid  = threadIdx.x;
  const int gb   = blockIdx.x & 3;    // batch group
  const int gh   = blockIdx.x >> 2;   // hidden group
  const int hs   = gh * HB;
  const int wv   = tid >> 6;
  const int lane = tid & 63;
  const int bm   = gb * BB + wv * 16; // this wave's batch-row base
  const int lm   = lane & 15;
  const int lq   = lane >> 4;
  const int koff = lq * 8;
  unsigned* cnt = barbase + gb * 64;  // per-group counter (256B apart)

  // ---- one-time: stage weight slices into LDS as bf16 ----
  for (int r = 0; r < 48; ++r) {
    const int g = r >> 4, j = r & 15;
    const int gr = g * kH + hs + j;   // row in 3H packing [r,z,n]
    for (int k = tid; k < W0K; k += NTHR) {
      float v = (k < kH) ? Whh0[gr * kH + k] : Wih0[gr * kF + (k - kH)];
      w0[r * W0S + k] = (bf16_t)v;
    }
    for (int k = tid; k < W1K; k += NTHR) {
      float v = (k < kH) ? Whh1[gr * kH + k] : Wih1[gr * kH + (k - kH)];
      w1[r * W1S + k] = (bf16_t)v;
    }
  }

  const int c = hs + lm;              // this lane's hidden column
  const float b0r  = bih0[c] + bhh0[c];
  const float b0z  = bih0[kH + c] + bhh0[kH + c];
  const float b0nx = bih0[2 * kH + c];
  const float b0nh = bhh0[2 * kH + c];
  const float b1r  = bih1[c] + bhh1[c];
  const float b1z  = bih1[kH + c] + bhh1[kH + c];
  const float b1nx = bih1[2 * kH + c];
  const float b1nh = bhh1[2 * kH + c];

  // register-resident hidden master state: rows bm+lq*4+i, col c
  float h0m[4] = {0.f, 0.f, 0.f, 0.f};
  float h1m[4] = {0.f, 0.f, 0.f, 0.f};

  __syncthreads();

  const int arow  = bm + lm;
  const int arowH = arow * kH;

  for (int s = 0; s < kT + 1; ++s) {
    const int pr = (s + 1) & 1;       // read parity (prev step)
    const int pw = s & 1;             // write parity

    // ================= layer 0 : t = s =================
    if (s < kT) {
      // x_t loaded first (issue early; independent of h loads)
      const float* xp = seq + ((size_t)arow * kT + s) * kF + koff;
      bf16x8 ax;
#pragma unroll
      for (int j = 0; j < 8; ++j) ax[j] = (bf16_t)xp[j];

      const bf16_t* hsrc = h0b + pr * (kB * kH);
      f32x4 aR{0.f, 0.f, 0.f, 0.f}, aZ{0.f, 0.f, 0.f, 0.f};
      f32x4 aNH{0.f, 0.f, 0.f, 0.f}, aNX{0.f, 0.f, 0.f, 0.f};

#pragma unroll 4
      for (int kc = 0; kc < 16; ++kc) {   // K = h0 (512)
        bf16x8 a = *(const bf16x8*)(hsrc + arowH + kc * 32 + koff);
        bf16x8 br = *(const bf16x8*)(w0 + (0 * 16 + lm) * W0S + kc * 32 + koff);
        bf16x8 bz = *(const bf16x8*)(w0 + (1 * 16 + lm) * W0S + kc * 32 + koff);
        bf16x8 bn = *(const bf16x8*)(w0 + (2 * 16 + lm) * W0S + kc * 32 + koff);
        aR  = __builtin_amdgcn_mfma_f32_16x16x32_bf16(a, br, aR, 0, 0, 0);
        aZ  = __builtin_amdgcn_mfma_f32_16x16x32_bf16(a, bz, aZ, 0, 0, 0);
        aNH = __builtin_amdgcn_mfma_f32_16x16x32_bf16(a, bn, aNH, 0, 0, 0);
      }
      {  // K = x_t (32)
        bf16x8 br = *(const bf16x8*)(w0 + (0 * 16 + lm) * W0S + kH + koff);
        bf16x8 bz = *(const bf16x8*)(w0 + (1 * 16 + lm) * W0S + kH + koff);
        bf16x8 bn = *(const bf16x8*)(w0 + (2 * 16 + lm) * W0S + kH + koff);
        aR  = __builtin_amdgcn_mfma_f32_16x16x32_bf16(ax, br, aR, 0, 0, 0);
        aZ  = __builtin_amdgcn_mfma_f32_16x16x32_bf16(ax, bz, aZ, 0, 0, 0);
        aNX = __builtin_amdgcn_mfma_f32_16x16x32_bf16(ax, bn, aNX, 0, 0, 0);
      }
      bf16_t* hnb = h0b + pw * (kB * kH);
#pragma unroll
      for (int i = 0; i < 4; ++i) {
        const int b = bm + lq * 4 + i;
        float r = sigmoid_f(aR[i] + b0r);
        float z = sigmoid_f(aZ[i] + b0z);
        float n = tanh_f((aNX[i] + b0nx) + r * (aNH[i] + b0nh));
        float hn = (1.f - z) * n + z * h0m[i];
        h0m[i] = hn;
        hnb[b * kH + c] = (bf16_t)hn;
      }
    }

    // ================= layer 1 : t = s-1 =================
    if (s >= 1) {
      const bf16_t* h1src = h1b + pr * (kB * kH);   // h1_{t-1}
      const bf16_t* xsrc  = h0b + pr * (kB * kH);   // out0_t
      f32x4 cR{0.f, 0.f, 0.f, 0.f}, cZ{0.f, 0.f, 0.f, 0.f};
      f32x4 cNH{0.f, 0.f, 0.f, 0.f}, cNX{0.f, 0.f, 0.f, 0.f};

#pragma unroll 4
      for (int kc = 0; kc < 16; ++kc) {   // fused: K=h1 and K=out0 together
        bf16x8 a1 = *(const bf16x8*)(h1src + arowH + kc * 32 + koff);
        bf16x8 a0 = *(const bf16x8*)(xsrc + arowH + kc * 32 + koff);
        bf16x8 br1 = *(const bf16x8*)(w1 + (0 * 16 + lm) * W1S + kc * 32 + koff);
        bf16x8 bz1 = *(const bf16x8*)(w1 + (1 * 16 + lm) * W1S + kc * 32 + koff);
        bf16x8 bn1 = *(const bf16x8*)(w1 + (2 * 16 + lm) * W1S + kc * 32 + koff);
        bf16x8 br0 = *(const bf16x8*)(w1 + (0 * 16 + lm) * W1S + kH + kc * 32 + koff);
        bf16x8 bz0 = *(const bf16x8*)(w1 + (1 * 16 + lm) * W1S + kH + kc * 32 + koff);
        bf16x8 bn0 = *(const bf16x8*)(w1 + (2 * 16 + lm) * W1S + kH + kc * 32 + koff);
        cR  = __builtin_amdgcn_mfma_f32_16x16x32_bf16(a1, br1, cR, 0, 0, 0);
        cZ  = __builtin_amdgcn_mfma_f32_16x16x32_bf16(a1, bz1, cZ, 0, 0, 0);
        cNH = __builtin_amdgcn_mfma_f32_16x16x32_bf16(a1, bn1, cNH, 0, 0, 0);
        cR  = __builtin_amdgcn_mfma_f32_16x16x32_bf16(a0, br0, cR, 0, 0, 0);
        cZ  = __builtin_amdgcn_mfma_f32_16x16x32_bf16(a0, bz0, cZ, 0, 0, 0);
        cNX = __builtin_amdgcn_mfma_f32_16x16x32_bf16(a0, bn0, cNX, 0, 0, 0);
      }
      bf16_t* hnb = h1b + pw * (kB * kH);
#pragma unroll
      for (int i = 0; i < 4; ++i) {
        const int b = bm + lq * 4 + i;
        float r = sigmoid_f(cR[i] + b1r);
        float z = sigmoid_f(cZ[i] + b1z);
        float n = tanh_f((cNX[i] + b1nx) + r * (cNH[i] + b1nh));
        float hn = (1.f - z) * n + z * h1m[i];
        h1m[i] = hn;
        hnb[b * kH + c] = (bf16_t)hn;
        if (s == kT) h1f[b * kH + c] = hn;  // final hidden for the head
      }
    }

    // ================= per-group barrier (32 blocks) =================
    __syncthreads();  // drains vmcnt: all block stores are in L2
    if (tid == 0) {
      __builtin_amdgcn_fence(__ATOMIC_RELEASE, "agent");   // L2 -> MALL once
      __hip_atomic_fetch_add(cnt, 1u, __ATOMIC_RELAXED,
                             __HIP_MEMORY_SCOPE_AGENT);
      const unsigned target = (unsigned)GRP * (unsigned)(s + 1);
      long guard = 0;
      while (__hip_atomic_load(cnt, __ATOMIC_RELAXED,
                               __HIP_MEMORY_SCOPE_AGENT) < target) {
        __builtin_amdgcn_s_sleep(2);
        if (++guard > (1L << 22)) break;  // co-residency guaranteed; never hangs
      }
      __builtin_amdgcn_fence(__ATOMIC_ACQUIRE, "agent");   // inv L1/L2 once
    }
    __syncthreads();
  }
}

// ---- head: concat(h1_last, embed) -> fc1+relu -> fc2 ----
__global__ void head_kernel(const float* __restrict__ h1,     // (B,H)
                            const int* __restrict__ ticker,   // (B,)
                            const float* __restrict__ etab,   // (5000,E)
                            const float* __restrict__ fc1w,   // (H, H+E)
                            const float* __restrict__ fc1b,   // (H,)
                            const float* __restrict__ fc2w,   // (PD, H)
                            const float* __restrict__ fc2b,   // (PD,)
                            float* __restrict__ out) {        // (B, PD)
  __shared__ float xin[4][kH + kE];
  __shared__ float y1[4][kH];
  const int tid = threadIdx.x;
  const int b0 = blockIdx.x * 4;

  for (int idx = tid; idx < 4 * (kH + kE); idx += 256) {
    const int r = idx / (kH + kE), k = idx % (kH + kE);
    const int b = b0 + r;
    xin[r][k] = (k < kH) ? h1[b * kH + k] : etab[ticker[b] * kE + (k - kH)];
  }
  __syncthreads();

#pragma unroll
  for (int jj = 0; jj < 2; ++jj) {
    const int j = tid + jj * 256;
    const float* wr = fc1w + j * (kH + kE);
    float a0 = 0.f, a1 = 0.f, a2 = 0.f, a3 = 0.f;
    for (int k = 0; k < kH + kE; ++k) {
      const float w = wr[k];
      a0 += w * xin[0][k];
      a1 += w * xin[1][k];
      a2 += w * xin[2][k];
      a3 += w * xin[3][k];
    }
    const float bb = fc1b[j];
    y1[0][j] = fmaxf(a0 + bb, 0.f);
    y1[1][j] = fmaxf(a1 + bb, 0.f);
    y1[2][j] = fmaxf(a2 + bb, 0.f);
    y1[3][j] = fmaxf(a3 + bb, 0.f);
  }
  __syncthreads();

  if (tid < 4 * kPD) {
    const int r = tid / kPD, j = tid % kPD;
    const float* wr = fc2w + j * kH;
    float acc = fc2b[j];
    for (int k = 0; k < kH; ++k) acc += wr[k] * y1[r][k];
    out[(b0 + r) * kPD + j] = acc;
  }
}

extern "C" void kernel_launch(void* const* d_in, const int* in_sizes, int n_in,
                              void* d_out, int out_size, void* d_ws,
                              size_t ws_size, hipStream_t stream) {
  (void)in_sizes; (void)n_in; (void)out_size; (void)ws_size;

  const int*   ticker = (const int*)d_in[0];
  const float* seq    = (const float*)d_in[1];
  const float* etab   = (const float*)d_in[2];
  const float* Wih0   = (const float*)d_in[3];
  const float* Whh0   = (const float*)d_in[4];
  const float* bih0   = (const float*)d_in[5];
  const float* bhh0   = (const float*)d_in[6];
  const float* Wih1   = (const float*)d_in[7];
  const float* Whh1   = (const float*)d_in[8];
  const float* bih1   = (const float*)d_in[9];
  const float* bhh1   = (const float*)d_in[10];
  const float* fc1w   = (const float*)d_in[11];
  const float* fc1b   = (const float*)d_in[12];
  const float* fc2w   = (const float*)d_in[13];
  const float* fc2b   = (const float*)d_in[14];

  char* ws = (char*)d_ws;
  unsigned* bar = (unsigned*)ws;
  bf16_t* h0b = (bf16_t*)(ws + 1024);
  bf16_t* h1b = (bf16_t*)(ws + 1024 + 2 * kB * kH * 2);
  float*  h1f = (float*)(ws + 1024 + 4 * kB * kH * 2);
  const size_t init_bytes = 1024 + 4 * kB * kH * 2;  // counters + bf16 states

  hipMemsetAsync(d_ws, 0, init_bytes, stream);

  gru_persistent<<<GBLK, NTHR, LDSB, stream>>>(
      seq, Wih0, Whh0, bih0, bhh0, Wih1, Whh1, bih1, bhh1,
      h0b, h1b, h1f, bar);

  head_kernel<<<kB / 4, 256, 0, stream>>>(h1f, ticker, etab, fc1w, fc1b, fc2w,
                                          fc2b, (float*)d_out);
}